// Round 1
// baseline (605.874 us; speedup 1.0000x reference)
//
#include <hip/hip_runtime.h>
#include <hip/hip_bf16.h>

// Problem constants
#define BQ    256
#define NKEY  100000
#define DD    512
#define AD    256
#define CD    100
#define KSEL  32
#define KB    64            // keys per K1 block
#define NB    1563          // ceil(NKEY/KB)
#define TL    12            // per-thread top list (K2)
#define WT    40            // per-wave merged top (K2)
#define NCAND (4*WT)        // 160 rescore candidates

typedef __attribute__((ext_vector_type(8))) short  short8_t;
typedef __attribute__((ext_vector_type(8))) __bf16 bf16x8;
typedef __attribute__((ext_vector_type(4))) float  f32x4;

__device__ __forceinline__ unsigned short f2bf(float x) {
  unsigned int u = __float_as_uint(x);
  return (unsigned short)((u + 0x7FFFu + ((u >> 16) & 1u)) >> 16);  // RTNE
}
__device__ __forceinline__ float bf2f(unsigned short h) {
  return __uint_as_float(((unsigned int)h) << 16);
}
__device__ __forceinline__ f32x4 mfma_bf16(short8_t a, short8_t b, f32x4 c) {
  return __builtin_amdgcn_mfma_f32_16x16x32_bf16(
      __builtin_bit_cast(bf16x8, a), __builtin_bit_cast(bf16x8, b), c, 0, 0, 0);
}

template<int T>
__device__ __forceinline__ void topk_insert(float (&v)[T], int (&ix)[T], float val, int idx) {
  if (val <= v[T-1]) return;
  v[T-1] = val; ix[T-1] = idx;
  #pragma unroll
  for (int j = T-1; j > 0; --j) {
    bool sw = v[j] > v[j-1];
    float tv = sw ? v[j] : v[j-1];  float uv = sw ? v[j-1] : v[j];
    int   ti = sw ? ix[j] : ix[j-1]; int  ui = sw ? ix[j-1] : ix[j];
    v[j-1] = tv; v[j] = uv; ix[j-1] = ti; ix[j] = ui;
  }
}

// ---------------- K0: q = relu(query_feat); qn; q -> bf16 A-fragment layout ----------------
__global__ __launch_bounds__(256) void k0_prep(const float* __restrict__ qfeat,
                                               float* __restrict__ qr,
                                               unsigned short* __restrict__ qf,
                                               float* __restrict__ qn) {
  int b = blockIdx.x, t = threadIdx.x;
  float s = 0.f;
  #pragma unroll
  for (int p = 0; p < 2; ++p) {
    int k = t + p*256;
    float v = qfeat[b*DD + k];
    v = v > 0.f ? v : 0.f;
    qr[b*DD + k] = v;
    qf[(((b>>4)*64 + (k>>3))*16 + (b&15))*8 + (k&7)] = f2bf(v);
    s += v*v;
  }
  __shared__ float red[4];
  #pragma unroll
  for (int st = 1; st < 64; st <<= 1) s += __shfl_xor(s, st, 64);
  if ((t & 63) == 0) red[t>>6] = s;
  __syncthreads();
  if (t == 0) qn[b] = sqrtf(red[0]+red[1]+red[2]+red[3]);
}

// ---------------- K0b: Wm -> bf16 B-fragment layout ----------------
__global__ __launch_bounds__(256) void k0b_wmfrag(const float* __restrict__ Wm,
                                                  unsigned short* __restrict__ wmf) {
  int i = blockIdx.x*256 + threadIdx.x;   // i = d*256 + a, 131072 total
  int d = i >> 8, a = i & 255;
  wmf[(((a>>4)*64 + (d>>3))*16 + (a&15))*8 + (d&7)] = f2bf(Wm[i]);
}

// ---------------- K1: coarse bf16 GEMM (256q x 64k per wg) + key norms + per-block top-8 ----------------
__global__ __launch_bounds__(256) void k1_sim(const float* __restrict__ keys,
                                              const unsigned short* __restrict__ qf,
                                              float* __restrict__ kn,
                                              float* __restrict__ candv,
                                              int* __restrict__ candi) {
  __shared__ unsigned short bt[64*72];   // keys tile bf16, pad 72 (2-way free)
  __shared__ float kpart[64*16];
  __shared__ float invkn[64];
  __shared__ float simL[128*68];

  int b = blockIdx.x, t = threadIdx.x;
  int kb0 = b*KB;
  int w = t >> 6, l = t & 63, g = l >> 4, c = l & 15;

  f32x4 acc[4][4];
  #pragma unroll
  for (int m = 0; m < 4; ++m)
    #pragma unroll
    for (int n = 0; n < 4; ++n) acc[m][n] = (f32x4){0.f,0.f,0.f,0.f};
  float ksq[4] = {0.f,0.f,0.f,0.f};

  const short8_t* qf8 = (const short8_t*)qf;

  for (int st8 = 0; st8 < 8; ++st8) {       // K loop, BK=64
    __syncthreads();                        // protect bt reuse
    #pragma unroll
    for (int i = 0; i < 4; ++i) {           // stage 64keys x 64dims fp32 -> bf16 LDS
      int f = t + i*256;
      int r = f >> 4, c4 = f & 15;
      int key = kb0 + r;
      float4 v = make_float4(0.f,0.f,0.f,0.f);
      if (key < NKEY) v = *(const float4*)(keys + (size_t)key*DD + st8*64 + c4*4);
      ksq[i] += v.x*v.x + v.y*v.y + v.z*v.z + v.w*v.w;
      ushort4 h; h.x = f2bf(v.x); h.y = f2bf(v.y); h.z = f2bf(v.z); h.w = f2bf(v.w);
      *(ushort4*)&bt[r*72 + c4*4] = h;
    }
    __syncthreads();
    #pragma unroll
    for (int ks = 0; ks < 2; ++ks) {
      short8_t af[4], bf[4];
      int kt = st8*8 + ks*4 + g;
      #pragma unroll
      for (int m = 0; m < 4; ++m) af[m] = qf8[((w*4 + m)*64 + kt)*16 + c];
      #pragma unroll
      for (int n = 0; n < 4; ++n) bf[n] = *(const short8_t*)&bt[(n*16 + c)*72 + ks*32 + g*8];
      #pragma unroll
      for (int m = 0; m < 4; ++m)
        #pragma unroll
        for (int n = 0; n < 4; ++n) acc[m][n] = mfma_bf16(af[m], bf[n], acc[m][n]);
    }
  }

  // key norms
  #pragma unroll
  for (int i = 0; i < 4; ++i) kpart[((t>>4) + 16*i)*16 + (t&15)] = ksq[i];
  __syncthreads();
  if (t < 64) {
    float s2 = 0.f;
    #pragma unroll
    for (int i = 0; i < 16; ++i) s2 += kpart[t*16 + i];
    if (kb0 + t < NKEY) kn[kb0 + t] = sqrtf(s2);
    invkn[t] = s2 > 0.f ? rsqrtf(s2) : 0.f;
  }
  __syncthreads();

  // two phases: write sims (128 query rows) -> per-row top-8 -> candidates
  for (int ph = 0; ph < 2; ++ph) {
    if ((w >> 1) == ph) {
      int wl = w & 1;
      #pragma unroll
      for (int n = 0; n < 4; ++n) {
        int col = n*16 + c;
        float ik = invkn[col];
        bool valid = (kb0 + col) < NKEY;
        #pragma unroll
        for (int m = 0; m < 4; ++m)
          #pragma unroll
          for (int r = 0; r < 4; ++r) {
            int row = wl*64 + m*16 + g*4 + r;
            simL[row*68 + col] = valid ? acc[m][n][r] * ik : -1e30f;
          }
      }
    }
    __syncthreads();
    if (t < 128) {
      int q = ph*128 + t;
      float v[8]; int ix[8];
      #pragma unroll
      for (int j = 0; j < 8; ++j) { v[j] = -1e30f; ix[j] = 0; }
      for (int cc = 0; cc < 64; ++cc)
        topk_insert<8>(v, ix, simL[t*68 + cc], kb0 + cc);
      size_t cb = ((size_t)q*NB + b)*8;
      #pragma unroll
      for (int j = 0; j < 8; ++j) { candv[cb + j] = v[j]; candi[cb + j] = ix[j]; }
    }
    __syncthreads();
  }
}

// ---------------- K2: per-query merge -> exact fp32 rescore of 160 -> final top-32 idx ----------------
__global__ __launch_bounds__(256) void k2_select(const float* __restrict__ candv,
                                                 const int* __restrict__ candi,
                                                 const float* __restrict__ qr,
                                                 const float* __restrict__ qn,
                                                 const float* __restrict__ kn,
                                                 const float* __restrict__ keys,
                                                 int* __restrict__ fidx) {
  int q = blockIdx.x, t = threadIdx.x, w = t >> 6, l = t & 63;
  __shared__ int   wtop[NCAND];
  __shared__ float simx[NCAND];
  __shared__ int   sidx[NCAND];

  float v[TL]; int ix[TL];
  #pragma unroll
  for (int j = 0; j < TL; ++j) { v[j] = -INFINITY; ix[j] = -1; }
  size_t base = (size_t)q * (NB*8);
  for (int f = t; f < NB*8; f += 256)
    topk_insert<TL>(v, ix, candv[base + f], candi[base + f]);

  // wave-level k-way merge: exact wave top-WT (heads of sorted per-lane lists)
  for (int it = 0; it < WT; ++it) {
    float bv = v[0]; int bx = ix[0]; int bl = l;
    #pragma unroll
    for (int sft = 1; sft < 64; sft <<= 1) {
      float ov = __shfl_xor(bv, sft, 64);
      int  oxx = __shfl_xor(bx, sft, 64);
      int  ol  = __shfl_xor(bl, sft, 64);
      bool take = (ov > bv) || (ov == bv && ol < bl);
      if (take) { bv = ov; bx = oxx; bl = ol; }
    }
    if (l == 0) wtop[w*WT + it] = bx;
    if (l == bl) {
      #pragma unroll
      for (int j = 0; j < TL-1; ++j) { v[j] = v[j+1]; ix[j] = ix[j+1]; }
      v[TL-1] = -INFINITY; ix[TL-1] = -1;
    }
  }
  __syncthreads();

  // exact fp32 rescore (reference formula)
  if (t < NCAND) {
    int idx = wtop[t];
    int cidx = idx < 0 ? 0 : idx;
    const float4* kr  = (const float4*)(keys + (size_t)cidx*DD);
    const float4* qq4 = (const float4*)(qr + q*DD);
    float dot = 0.f;
    for (int d4 = 0; d4 < DD/4; ++d4) {
      float4 a = qq4[d4], bb = kr[d4];
      dot += a.x*bb.x + a.y*bb.y + a.z*bb.z + a.w*bb.w;
    }
    float den = fmaxf(qn[q]*kn[cidx], 1e-8f);
    simx[t] = (idx < 0) ? -INFINITY : dot/den;
    sidx[t] = cidx;
  }
  __syncthreads();

  // final exact top-32 of 160 (wave 0), tie-break: lower index first (lax.top_k)
  if (w == 0) {
    float a0 = simx[l], a1 = simx[l+64];
    int   i0 = sidx[l], i1 = sidx[l+64];
    float a2 = -INFINITY; int i2 = 0x7fffffff;
    if (l < NCAND - 128) { a2 = simx[l+128]; i2 = sidx[l+128]; }
    for (int it = 0; it < KSEL; ++it) {
      float bv = a0; int bx = i0; int slot = 0;
      if (a1 > bv || (a1 == bv && i1 < bx)) { bv = a1; bx = i1; slot = 1; }
      if (a2 > bv || (a2 == bv && i2 < bx)) { bv = a2; bx = i2; slot = 2; }
      int bl = l;
      #pragma unroll
      for (int sft = 1; sft < 64; sft <<= 1) {
        float ov = __shfl_xor(bv, sft, 64);
        int  oxx = __shfl_xor(bx, sft, 64);
        int  ol  = __shfl_xor(bl, sft, 64);
        bool take = (ov > bv) || (ov == bv && oxx < bx);
        if (take) { bv = ov; bx = oxx; bl = ol; }
      }
      if (l == 0) fidx[q*KSEL + it] = bx;
      if (l == bl) {
        if (slot == 0) a0 = -INFINITY; else if (slot == 1) a1 = -INFINITY; else a2 = -INFINITY;
      }
    }
  }
}

// ---------------- K3: gather knn, MFMA knn@Wm, tanh/score/softmax, attended, classify ----------------
__global__ __launch_bounds__(256) void k3_attn(const float* __restrict__ keys,
                                               const float* __restrict__ qr,
                                               const unsigned short* __restrict__ wmf,
                                               const int* __restrict__ fidx,
                                               const float* __restrict__ Wq,
                                               const float* __restrict__ bq,
                                               const float* __restrict__ bm,
                                               const float* __restrict__ Ws,
                                               const float* __restrict__ bsc,
                                               const float* __restrict__ Wc,
                                               const float* __restrict__ bc,
                                               float* __restrict__ out) {
  int q = blockIdx.x, t = threadIdx.x, w = t >> 6, l = t & 63, g = l >> 4, c = l & 15;
  __shared__ float qrl[512];
  __shared__ float qqb[256];
  __shared__ float wsl[256];
  __shared__ unsigned short knnb[32*520];   // knn bf16, pad 520
  __shared__ float spart[4][32];
  __shared__ float wexp[32];
  __shared__ float att[512];
  __shared__ int fl[32];

  if (t < 32) fl[t] = fidx[q*KSEL + t];
  qrl[t]       = qr[q*DD + t];
  qrl[t + 256] = qr[q*DD + 256 + t];
  __syncthreads();

  for (int r = 0; r < 32; ++r) {
    int row = fl[r];
    #pragma unroll
    for (int p = 0; p < 2; ++p) {
      int d = t + p*256;
      knnb[r*520 + d] = f2bf(keys[(size_t)row*DD + d]);
    }
  }
  {
    float s = bq[t] + bm[t];
    for (int d = 0; d < DD; ++d) s += qrl[d] * Wq[d*AD + t];
    qqb[t] = s;
    wsl[t] = Ws[t];
  }
  __syncthreads();

  f32x4 acc[2][4];
  #pragma unroll
  for (int m = 0; m < 2; ++m)
    #pragma unroll
    for (int n = 0; n < 4; ++n) acc[m][n] = (f32x4){0.f,0.f,0.f,0.f};
  const short8_t* wmf8 = (const short8_t*)wmf;
  for (int ks = 0; ks < 16; ++ks) {
    short8_t af[2], bf[4];
    #pragma unroll
    for (int m = 0; m < 2; ++m) af[m] = *(const short8_t*)&knnb[(m*16 + c)*520 + ks*32 + g*8];
    #pragma unroll
    for (int n = 0; n < 4; ++n) bf[n] = wmf8[((w*4 + n)*64 + ks*4 + g)*16 + c];
    #pragma unroll
    for (int m = 0; m < 2; ++m)
      #pragma unroll
      for (int n = 0; n < 4; ++n) acc[m][n] = mfma_bf16(af[m], bf[n], acc[m][n]);
  }

  float p[8] = {0.f,0.f,0.f,0.f,0.f,0.f,0.f,0.f};
  #pragma unroll
  for (int n = 0; n < 4; ++n) {
    int a = w*64 + n*16 + c;
    float qv = qqb[a], wv = wsl[a];
    #pragma unroll
    for (int m = 0; m < 2; ++m)
      #pragma unroll
      for (int r = 0; r < 4; ++r)
        p[m*4 + r] += tanhf(acc[m][n][r] + qv) * wv;
  }
  #pragma unroll
  for (int sft = 1; sft < 16; sft <<= 1)
    #pragma unroll
    for (int i = 0; i < 8; ++i) p[i] += __shfl_xor(p[i], sft, 64);
  if (c == 0) {
    #pragma unroll
    for (int m = 0; m < 2; ++m)
      #pragma unroll
      for (int r = 0; r < 4; ++r) spart[w][m*16 + g*4 + r] = p[m*4 + r];
  }
  __syncthreads();

  if (t < 32) {
    float s = spart[0][t] + spart[1][t] + spart[2][t] + spart[3][t] + bsc[0];
    float mx = s;
    #pragma unroll
    for (int sft = 1; sft < 32; sft <<= 1) mx = fmaxf(mx, __shfl_xor(mx, sft, 64));
    float e = expf(s - mx);
    float su = e;
    #pragma unroll
    for (int sft = 1; sft < 32; sft <<= 1) su += __shfl_xor(su, sft, 64);
    wexp[t] = e / su;
  }
  __syncthreads();

  #pragma unroll
  for (int pth = 0; pth < 2; ++pth) {
    int d = t + pth*256;
    float s = 0.f;
    #pragma unroll
    for (int k = 0; k < 32; ++k) s += wexp[k] * bf2f(knnb[k*520 + d]);
    att[d] = s;
  }
  __syncthreads();

  if (t < CD) {
    float o = bc[t];
    for (int j = 0; j < 512; ++j) o += qrl[j] * Wc[j*CD + t];
    for (int j = 0; j < 512; ++j) o += att[j] * Wc[(512 + j)*CD + t];
    out[q*CD + t] = o;
  }
}

// ---------------- launch ----------------
extern "C" void kernel_launch(void* const* d_in, const int* in_sizes, int n_in,
                              void* d_out, int out_size, void* d_ws, size_t ws_size,
                              hipStream_t stream) {
  const float* qfeat = (const float*)d_in[0];
  const float* keys  = (const float*)d_in[1];
  const float* Wq    = (const float*)d_in[2];
  const float* bq    = (const float*)d_in[3];
  const float* Wm    = (const float*)d_in[4];
  const float* bm    = (const float*)d_in[5];
  const float* Ws    = (const float*)d_in[6];
  const float* bsc   = (const float*)d_in[7];
  const float* Wc    = (const float*)d_in[8];
  const float* bc    = (const float*)d_in[9];
  float* out = (float*)d_out;

  char* ws = (char*)d_ws;
  unsigned short* qf   = (unsigned short*)(ws + 0);          // 262144 B
  float*          qr   = (float*)(ws + 262144);              // 524288 B
  float*          qn   = (float*)(ws + 786432);              // 1024 B
  float*          kn   = (float*)(ws + 787456);              // 400000 B
  unsigned short* wmf  = (unsigned short*)(ws + 1187584);    // 262144 B (128-aligned)
  float*          candv= (float*)(ws + 1449728);             // 12804096 B
  int*            candi= (int*)(ws + 14253824);              // 12804096 B
  int*            fidx = (int*)(ws + 27057920);              // 32768 B

  k0_prep  <<<BQ,   256, 0, stream>>>(qfeat, qr, qf, qn);
  k0b_wmfrag<<<512, 256, 0, stream>>>(Wm, wmf);
  k1_sim   <<<NB,   256, 0, stream>>>(keys, qf, kn, candv, candi);
  k2_select<<<BQ,   256, 0, stream>>>(candv, candi, qr, qn, kn, keys, fidx);
  k3_attn  <<<BQ,   256, 0, stream>>>(keys, qr, wmf, fidx, Wq, bq, bm, Ws, bsc, Wc, bc, out);
}

// Round 2
// 333.835 us; speedup vs baseline: 1.8149x; 1.8149x over previous
//
#include <hip/hip_runtime.h>
#include <hip/hip_bf16.h>
#include <hip/hip_fp16.h>

// Problem constants
#define BQ    256
#define NKEY  100000
#define DD    512
#define AD    256
#define CD    100
#define KSEL  32
#define KB    64            // keys per K1 block
#define NB    1563          // ceil(NKEY/KB)
#define TL    12            // per-thread top list (K2)
#define WT    40            // per-wave merged top (K2)
#define NCAND (4*WT)        // 160 rescore candidates

typedef __attribute__((ext_vector_type(8))) short  short8_t;
typedef __attribute__((ext_vector_type(8))) __bf16 bf16x8;
typedef __attribute__((ext_vector_type(4))) float  f32x4;

__device__ __forceinline__ unsigned short f2bf(float x) {
  unsigned int u = __float_as_uint(x);
  return (unsigned short)((u + 0x7FFFu + ((u >> 16) & 1u)) >> 16);  // RTNE
}
__device__ __forceinline__ unsigned short f2bf_n(float x) {
  __bf16 h = (__bf16)x;                 // native cvt (RTNE), pairs into v_cvt_pk_bf16_f32
  return __builtin_bit_cast(unsigned short, h);
}
__device__ __forceinline__ float bf2f(unsigned short h) {
  return __uint_as_float(((unsigned int)h) << 16);
}
__device__ __forceinline__ f32x4 mfma_bf16(short8_t a, short8_t b, f32x4 c) {
  return __builtin_amdgcn_mfma_f32_16x16x32_bf16(
      __builtin_bit_cast(bf16x8, a), __builtin_bit_cast(bf16x8, b), c, 0, 0, 0);
}
__device__ __forceinline__ float fast_tanh(float x) {
  x = fminf(fmaxf(x, -15.f), 15.f);
  float e = __expf(2.f * x);
  return (e - 1.f) * __builtin_amdgcn_rcpf(e + 1.f);
}

template<int T>
__device__ __forceinline__ void topk_insert(float (&v)[T], int (&ix)[T], float val, int idx) {
  if (val <= v[T-1]) return;
  v[T-1] = val; ix[T-1] = idx;
  #pragma unroll
  for (int j = T-1; j > 0; --j) {
    bool sw = v[j] > v[j-1];
    float tv = sw ? v[j] : v[j-1];  float uv = sw ? v[j-1] : v[j];
    int   ti = sw ? ix[j] : ix[j-1]; int  ui = sw ? ix[j-1] : ix[j];
    v[j-1] = tv; v[j] = uv; ix[j-1] = ti; ix[j] = ui;
  }
}

// ---------------- K0: q = relu(query_feat); qn; q -> bf16 fragment layout ----------------
__global__ __launch_bounds__(256) void k0_prep(const float* __restrict__ qfeat,
                                               float* __restrict__ qr,
                                               unsigned short* __restrict__ qf,
                                               float* __restrict__ qn) {
  int b = blockIdx.x, t = threadIdx.x;
  float s = 0.f;
  #pragma unroll
  for (int p = 0; p < 2; ++p) {
    int k = t + p*256;
    float v = qfeat[b*DD + k];
    v = v > 0.f ? v : 0.f;
    qr[b*DD + k] = v;
    qf[(((b>>4)*64 + (k>>3))*16 + (b&15))*8 + (k&7)] = f2bf(v);
    s += v*v;
  }
  __shared__ float red[4];
  #pragma unroll
  for (int st = 1; st < 64; st <<= 1) s += __shfl_xor(s, st, 64);
  if ((t & 63) == 0) red[t>>6] = s;
  __syncthreads();
  if (t == 0) qn[b] = sqrtf(red[0]+red[1]+red[2]+red[3]);
}

// ---------------- K0b: [512,256] fp32 matrix -> bf16 B-fragment layout ----------------
__global__ __launch_bounds__(256) void k0b_frag(const float* __restrict__ W,
                                                unsigned short* __restrict__ wf) {
  int i = blockIdx.x*256 + threadIdx.x;   // i = d*256 + a, 131072 total
  int d = i >> 8, a = i & 255;
  wf[(((a>>4)*64 + (d>>3))*16 + (a&15))*8 + (d&7)] = f2bf(W[i]);
}

// ---------------- K_qq: qq = relu(q) @ Wq + bq + bm  (256x256, K=512 MFMA) ----------------
__global__ __launch_bounds__(256) void k_qq(const float* __restrict__ Wq,
                                            const unsigned short* __restrict__ qf,
                                            const float* __restrict__ bq,
                                            const float* __restrict__ bm,
                                            float* __restrict__ qq) {
  __shared__ unsigned short wb[64*16*8];   // 16 KB
  int bn = blockIdx.x, t = threadIdx.x;
  int w = t >> 6, l = t & 63, g = l >> 4, c = l & 15;
  #pragma unroll
  for (int i = 0; i < 32; ++i) {
    int d = i*16 + (t>>4); int a = t & 15;
    wb[((d>>3)*16 + a)*8 + (d&7)] = f2bf(Wq[d*AD + bn*16 + a]);
  }
  __syncthreads();
  const short8_t* qf8 = (const short8_t*)qf;
  const short8_t* wb8 = (const short8_t*)wb;
  f32x4 acc[4];
  #pragma unroll
  for (int m = 0; m < 4; ++m) acc[m] = (f32x4){0.f,0.f,0.f,0.f};
  for (int kt = 0; kt < 16; ++kt) {
    short8_t bfr = wb8[(kt*4 + g)*16 + c];
    #pragma unroll
    for (int m = 0; m < 4; ++m) {
      short8_t afr = qf8[((w*4 + m)*64 + kt*4 + g)*16 + c];
      acc[m] = mfma_bf16(afr, bfr, acc[m]);
    }
  }
  int col = bn*16 + c;
  float bias = bq[col] + bm[col];
  #pragma unroll
  for (int m = 0; m < 4; ++m)
    #pragma unroll
    for (int r = 0; r < 4; ++r)
      qq[(w*64 + m*16 + g*4 + r)*AD + col] = acc[m][r] + bias;
}

// ---------------- K1: coarse bf16 GEMM (keys=A, queries=B) + in-register per-lane top-3 ----------------
__global__ __launch_bounds__(256) void k1_sim(const float* __restrict__ keys,
                                              const unsigned short* __restrict__ qf,
                                              unsigned int* __restrict__ cand) {
  __shared__ unsigned short bt[64*72];   // key tile bf16
  __shared__ float kpart[64*16];
  __shared__ float invkn[64];

  int b = blockIdx.x, t = threadIdx.x;
  int kb0 = b*KB;
  int w = t >> 6, l = t & 63, g = l >> 4, c = l & 15;

  f32x4 acc[4][4];   // [key-tile m][query-tile n]
  #pragma unroll
  for (int m = 0; m < 4; ++m)
    #pragma unroll
    for (int n = 0; n < 4; ++n) acc[m][n] = (f32x4){0.f,0.f,0.f,0.f};
  float ksq[4] = {0.f,0.f,0.f,0.f};

  const short8_t* qf8 = (const short8_t*)qf;

  for (int st8 = 0; st8 < 8; ++st8) {
    __syncthreads();
    #pragma unroll
    for (int i = 0; i < 4; ++i) {
      int f = t + i*256;
      int r = f >> 4, c4 = f & 15;
      int key = kb0 + r;
      float4 v = make_float4(0.f,0.f,0.f,0.f);
      if (key < NKEY) v = *(const float4*)(keys + (size_t)key*DD + st8*64 + c4*4);
      ksq[i] += v.x*v.x + v.y*v.y + v.z*v.z + v.w*v.w;
      ushort4 h; h.x = f2bf_n(v.x); h.y = f2bf_n(v.y); h.z = f2bf_n(v.z); h.w = f2bf_n(v.w);
      *(ushort4*)&bt[r*72 + c4*4] = h;
    }
    __syncthreads();
    #pragma unroll
    for (int ks = 0; ks < 2; ++ks) {
      short8_t af[4], bf[4];
      int kt = st8*8 + ks*4 + g;
      #pragma unroll
      for (int m = 0; m < 4; ++m) af[m] = *(const short8_t*)&bt[(m*16 + c)*72 + ks*32 + g*8];
      #pragma unroll
      for (int n = 0; n < 4; ++n) bf[n] = qf8[((w*4 + n)*64 + kt)*16 + c];
      #pragma unroll
      for (int m = 0; m < 4; ++m)
        #pragma unroll
        for (int n = 0; n < 4; ++n) acc[m][n] = mfma_bf16(af[m], bf[n], acc[m][n]);
    }
  }

  // key inverse norms
  #pragma unroll
  for (int i = 0; i < 4; ++i) kpart[((t>>4) + 16*i)*16 + (t&15)] = ksq[i];
  __syncthreads();
  if (t < 64) {
    float s2 = 0.f;
    #pragma unroll
    for (int i = 0; i < 16; ++i) s2 += kpart[t*16 + i];
    invkn[t] = s2 > 0.f ? rsqrtf(s2) : 0.f;
  }
  __syncthreads();

  float ikv[16];
  #pragma unroll
  for (int m = 0; m < 4; ++m)
    #pragma unroll
    for (int r = 0; r < 4; ++r) ikv[m*4 + r] = invkn[m*16 + g*4 + r];

  // per-lane branchless top-3 of the lane's 16 keys, per query column
  #pragma unroll
  for (int n = 0; n < 4; ++n) {
    float v1 = -3.0e38f, v2 = -3.0e38f, v3 = -3.0e38f;
    int   i1 = 0, i2 = 0, i3 = 0;
    #pragma unroll
    for (int m = 0; m < 4; ++m)
      #pragma unroll
      for (int r = 0; r < 4; ++r) {
        int lid = m*16 + g*4 + r;
        bool valid = (kb0 + lid) < NKEY;
        float v = valid ? acc[m][n][r] * ikv[m*4 + r] : -3.0e38f;
        bool gt1 = v > v1, gt2 = v > v2, gt3 = v > v3;
        v3 = gt2 ? v2 : (gt3 ? v : v3);  i3 = gt2 ? i2 : (gt3 ? lid : i3);
        v2 = gt1 ? v1 : (gt2 ? v : v2);  i2 = gt1 ? i1 : (gt2 ? lid : i2);
        v1 = gt1 ? v  : v1;              i1 = gt1 ? lid : i1;
      }
    int q = w*64 + n*16 + c;
    unsigned int base = ((unsigned int)q*NB + (unsigned int)b)*12u + (unsigned int)g*3u;
    cand[base + 0] = ((unsigned int)__half_as_ushort(__float2half(v1)) << 16) | (unsigned int)i1;
    cand[base + 1] = ((unsigned int)__half_as_ushort(__float2half(v2)) << 16) | (unsigned int)i2;
    cand[base + 2] = ((unsigned int)__half_as_ushort(__float2half(v3)) << 16) | (unsigned int)i3;
  }
}

// ---------------- K2: per-query merge -> exact fp32 rescore of 160 -> final top-32 idx ----------------
__global__ __launch_bounds__(256) void k2_select(const unsigned int* __restrict__ cand,
                                                 const float* __restrict__ qr,
                                                 const float* __restrict__ qn,
                                                 const float* __restrict__ keys,
                                                 int* __restrict__ fidx) {
  int q = blockIdx.x, t = threadIdx.x, w = t >> 6, l = t & 63;
  __shared__ int   wtop[NCAND];
  __shared__ float simx[NCAND];
  __shared__ int   sidx[NCAND];

  float v[TL]; int ix[TL];
  #pragma unroll
  for (int j = 0; j < TL; ++j) { v[j] = -INFINITY; ix[j] = -1; }
  const unsigned int* cq = cand + (size_t)q * (NB*12);
  int bb = t / 12, slot = t - bb*12;
  for (int i = t; i < NB*12; i += 256) {
    unsigned int p = cq[i];
    float val = __half2float(__ushort_as_half((unsigned short)(p >> 16)));
    int idx = (bb << 6) | (int)(p & 63u);
    topk_insert<TL>(v, ix, val, idx);
    slot += 4; bb += 21; if (slot >= 12) { slot -= 12; bb += 1; }
  }

  // wave-level merge: wave top-WT
  for (int it = 0; it < WT; ++it) {
    float bv = v[0]; int bx = ix[0]; int bl = l;
    #pragma unroll
    for (int sft = 1; sft < 64; sft <<= 1) {
      float ov = __shfl_xor(bv, sft, 64);
      int  oxx = __shfl_xor(bx, sft, 64);
      int  ol  = __shfl_xor(bl, sft, 64);
      bool take = (ov > bv) || (ov == bv && ol < bl);
      if (take) { bv = ov; bx = oxx; bl = ol; }
    }
    if (l == 0) wtop[w*WT + it] = bx;
    if (l == bl) {
      #pragma unroll
      for (int j = 0; j < TL-1; ++j) { v[j] = v[j+1]; ix[j] = ix[j+1]; }
      v[TL-1] = -INFINITY; ix[TL-1] = -1;
    }
  }
  __syncthreads();

  // exact fp32 rescore (reference formula; kn recomputed exactly from the same loads)
  if (t < NCAND) {
    int idx = wtop[t];
    bool bad = (idx < 0) || (idx >= NKEY);
    int cidx = bad ? 0 : idx;
    const float4* kr  = (const float4*)(keys + (size_t)cidx*DD);
    const float4* qq4 = (const float4*)(qr + q*DD);
    float dot = 0.f, ks = 0.f;
    for (int d4 = 0; d4 < DD/4; ++d4) {
      float4 a = qq4[d4], bv = kr[d4];
      dot += a.x*bv.x + a.y*bv.y + a.z*bv.z + a.w*bv.w;
      ks  += bv.x*bv.x + bv.y*bv.y + bv.z*bv.z + bv.w*bv.w;
    }
    float den = fmaxf(qn[q]*sqrtf(ks), 1e-8f);
    simx[t] = bad ? -1e30f : dot/den;
    sidx[t] = cidx;
  }
  __syncthreads();

  // final exact top-32 of 160 (wave 0), tie-break: lower index first (lax.top_k)
  if (w == 0) {
    float a0 = simx[l], a1 = simx[l+64];
    int   i0 = sidx[l], i1 = sidx[l+64];
    float a2 = -INFINITY; int i2 = 0x7fffffff;
    if (l < NCAND - 128) { a2 = simx[l+128]; i2 = sidx[l+128]; }
    for (int it = 0; it < KSEL; ++it) {
      float bv = a0; int bx = i0; int slot2 = 0;
      if (a1 > bv || (a1 == bv && i1 < bx)) { bv = a1; bx = i1; slot2 = 1; }
      if (a2 > bv || (a2 == bv && i2 < bx)) { bv = a2; bx = i2; slot2 = 2; }
      int bl = l;
      #pragma unroll
      for (int sft = 1; sft < 64; sft <<= 1) {
        float ov = __shfl_xor(bv, sft, 64);
        int  oxx = __shfl_xor(bx, sft, 64);
        int  ol  = __shfl_xor(bl, sft, 64);
        bool take = (ov > bv) || (ov == bv && oxx < bx);
        if (take) { bv = ov; bx = oxx; bl = ol; }
      }
      if (l == 0) fidx[q*KSEL + it] = bx;
      if (l == bl) {
        if (slot2 == 0) a0 = -INFINITY; else if (slot2 == 1) a1 = -INFINITY; else a2 = -INFINITY;
      }
    }
  }
}

// ---------------- K3a: gather knn, MFMA knn@Wm, tanh/score/softmax, attended -> attf ----------------
__global__ __launch_bounds__(256) void k3_attn(const float* __restrict__ keys,
                                               const float* __restrict__ qq,
                                               const unsigned short* __restrict__ wmf,
                                               const int* __restrict__ fidx,
                                               const float* __restrict__ Ws,
                                               const float* __restrict__ bsc,
                                               unsigned short* __restrict__ attf) {
  int q = blockIdx.x, t = threadIdx.x, w = t >> 6, l = t & 63, g = l >> 4, c = l & 15;
  __shared__ float qqb[256];
  __shared__ float wsl[256];
  __shared__ unsigned short knnb[32*520];
  __shared__ float spart[4][32];
  __shared__ float wexp[32];
  __shared__ int fl[32];

  if (t < 32) fl[t] = fidx[q*KSEL + t];
  qqb[t] = qq[q*AD + t];
  wsl[t] = Ws[t];
  __syncthreads();

  for (int r = 0; r < 32; ++r) {
    int row = fl[r];
    #pragma unroll
    for (int p = 0; p < 2; ++p) {
      int d = t + p*256;
      knnb[r*520 + d] = f2bf(keys[(size_t)row*DD + d]);
    }
  }
  __syncthreads();

  f32x4 acc[2][4];
  #pragma unroll
  for (int m = 0; m < 2; ++m)
    #pragma unroll
    for (int n = 0; n < 4; ++n) acc[m][n] = (f32x4){0.f,0.f,0.f,0.f};
  const short8_t* wmf8 = (const short8_t*)wmf;
  for (int ks = 0; ks < 16; ++ks) {
    short8_t af[2], bf[4];
    #pragma unroll
    for (int m = 0; m < 2; ++m) af[m] = *(const short8_t*)&knnb[(m*16 + c)*520 + ks*32 + g*8];
    #pragma unroll
    for (int n = 0; n < 4; ++n) bf[n] = wmf8[((w*4 + n)*64 + ks*4 + g)*16 + c];
    #pragma unroll
    for (int m = 0; m < 2; ++m)
      #pragma unroll
      for (int n = 0; n < 4; ++n) acc[m][n] = mfma_bf16(af[m], bf[n], acc[m][n]);
  }

  float p[8] = {0.f,0.f,0.f,0.f,0.f,0.f,0.f,0.f};
  #pragma unroll
  for (int n = 0; n < 4; ++n) {
    int a = w*64 + n*16 + c;
    float qv = qqb[a], wv = wsl[a];
    #pragma unroll
    for (int m = 0; m < 2; ++m)
      #pragma unroll
      for (int r = 0; r < 4; ++r)
        p[m*4 + r] += fast_tanh(acc[m][n][r] + qv) * wv;
  }
  #pragma unroll
  for (int sft = 1; sft < 16; sft <<= 1)
    #pragma unroll
    for (int i = 0; i < 8; ++i) p[i] += __shfl_xor(p[i], sft, 64);
  if (c == 0) {
    #pragma unroll
    for (int m = 0; m < 2; ++m)
      #pragma unroll
      for (int r = 0; r < 4; ++r) spart[w][m*16 + g*4 + r] = p[m*4 + r];
  }
  __syncthreads();

  if (t < 32) {
    float s = spart[0][t] + spart[1][t] + spart[2][t] + spart[3][t] + bsc[0];
    float mx = s;
    #pragma unroll
    for (int sft = 1; sft < 32; sft <<= 1) mx = fmaxf(mx, __shfl_xor(mx, sft, 64));
    float e = __expf(s - mx);
    float su = e;
    #pragma unroll
    for (int sft = 1; sft < 32; sft <<= 1) su += __shfl_xor(su, sft, 64);
    wexp[t] = e / su;
  }
  __syncthreads();

  #pragma unroll
  for (int pth = 0; pth < 2; ++pth) {
    int d = t + pth*256;
    float s = 0.f;
    #pragma unroll
    for (int k = 0; k < 32; ++k) s += wexp[k] * bf2f(knnb[k*520 + d]);
    attf[(((q>>4)*64 + (d>>3))*16 + (q&15))*8 + (d&7)] = f2bf(s);
  }
}

// ---------------- K3b: out = [q, attended] @ Wc + bc  (256x100, K=1024 MFMA) ----------------
__global__ __launch_bounds__(256) void k3b_cls(const float* __restrict__ Wc,
                                               const unsigned short* __restrict__ qf,
                                               const unsigned short* __restrict__ attf,
                                               const float* __restrict__ bc,
                                               float* __restrict__ out) {
  __shared__ unsigned short wb[128*16*8];   // 32 KB
  int bn = blockIdx.x, t = threadIdx.x;
  int w = t >> 6, l = t & 63, g = l >> 4, c = l & 15;
  #pragma unroll
  for (int i = 0; i < 64; ++i) {
    int d = i*16 + (t>>4); int a = t & 15;
    int col = bn*16 + a;
    float vv = (col < CD) ? Wc[d*CD + col] : 0.f;
    wb[((d>>3)*16 + a)*8 + (d&7)] = f2bf(vv);
  }
  __syncthreads();
  const short8_t* qf8 = (const short8_t*)qf;
  const short8_t* af8 = (const short8_t*)attf;
  const short8_t* wb8 = (const short8_t*)wb;
  f32x4 acc[4];
  #pragma unroll
  for (int m = 0; m < 4; ++m) acc[m] = (f32x4){0.f,0.f,0.f,0.f};
  for (int kt = 0; kt < 32; ++kt) {
    short8_t bfr = wb8[(kt*4 + g)*16 + c];
    const short8_t* asrc = (kt < 16) ? qf8 : af8;
    int kbase = (kt < 16) ? (kt*4 + g) : ((kt-16)*4 + g);
    #pragma unroll
    for (int m = 0; m < 4; ++m) {
      short8_t afr = asrc[((w*4 + m)*64 + kbase)*16 + c];
      acc[m] = mfma_bf16(afr, bfr, acc[m]);
    }
  }
  int col = bn*16 + c;
  if (col < CD) {
    float bias = bc[col];
    #pragma unroll
    for (int m = 0; m < 4; ++m)
      #pragma unroll
      for (int r = 0; r < 4; ++r)
        out[(w*64 + m*16 + g*4 + r)*CD + col] = acc[m][r] + bias;
  }
}

// ---------------- launch ----------------
extern "C" void kernel_launch(void* const* d_in, const int* in_sizes, int n_in,
                              void* d_out, int out_size, void* d_ws, size_t ws_size,
                              hipStream_t stream) {
  const float* qfeat = (const float*)d_in[0];
  const float* keys  = (const float*)d_in[1];
  const float* Wq    = (const float*)d_in[2];
  const float* bq    = (const float*)d_in[3];
  const float* Wm    = (const float*)d_in[4];
  const float* bm    = (const float*)d_in[5];
  const float* Ws    = (const float*)d_in[6];
  const float* bsc   = (const float*)d_in[7];
  const float* Wc    = (const float*)d_in[8];
  const float* bc    = (const float*)d_in[9];
  float* out = (float*)d_out;

  char* ws = (char*)d_ws;
  unsigned short* qf   = (unsigned short*)(ws + 0);          // 262144 B
  float*          qr   = (float*)(ws + 262144);              // 524288 B
  float*          qn   = (float*)(ws + 786432);              // 1024 B
  unsigned short* wmf  = (unsigned short*)(ws + 787456);     // 262144 B
  float*          qq   = (float*)(ws + 1049600);             // 262144 B
  unsigned short* attf = (unsigned short*)(ws + 1311744);    // 262144 B
  int*            fidx = (int*)(ws + 1573888);               // 32768 B
  unsigned int*   cand = (unsigned int*)(ws + 1606656);      // 19203072 B

  k0_prep  <<<BQ,  256, 0, stream>>>(qfeat, qr, qf, qn);
  k0b_frag <<<512, 256, 0, stream>>>(Wm, wmf);
  k_qq     <<<16,  256, 0, stream>>>(Wq, qf, bq, bm, qq);
  k1_sim   <<<NB,  256, 0, stream>>>(keys, qf, cand);
  k2_select<<<BQ,  256, 0, stream>>>(cand, qr, qn, keys, fidx);
  k3_attn  <<<BQ,  256, 0, stream>>>(keys, qq, wmf, fidx, Ws, bsc, attf);
  k3b_cls  <<<7,   256, 0, stream>>>(Wc, qf, attf, bc, out);
}

// Round 3
// 273.689 us; speedup vs baseline: 2.2137x; 1.2198x over previous
//
#include <hip/hip_runtime.h>
#include <hip/hip_bf16.h>
#include <hip/hip_fp16.h>

// Problem constants
#define BQ    256
#define NKEY  100000
#define DD    512
#define AD    256
#define CD    100
#define KSEL  32
#define KB    64            // keys per K1 block
#define NB    1563          // ceil(NKEY/KB)
#define CPQ   (NB*12)       // cand entries per query = 18756

// k2a/k2b selection params
#define NPART 8             // k2a blocks per query
#define WTOP  12            // per-wave top list emitted by k2a
#define NC2   (NPART*4*WTOP)  // 384 rescore candidates per query
#define TLA   6             // per-lane list depth in k2a

typedef __attribute__((ext_vector_type(8))) short  short8_t;
typedef __attribute__((ext_vector_type(8))) __bf16 bf16x8;
typedef __attribute__((ext_vector_type(4))) float  f32x4;

__device__ __forceinline__ unsigned short f2bf(float x) {
  unsigned int u = __float_as_uint(x);
  return (unsigned short)((u + 0x7FFFu + ((u >> 16) & 1u)) >> 16);  // RTNE
}
__device__ __forceinline__ unsigned short f2bf_n(float x) {
  __bf16 h = (__bf16)x;
  return __builtin_bit_cast(unsigned short, h);
}
__device__ __forceinline__ float bf2f(unsigned short h) {
  return __uint_as_float(((unsigned int)h) << 16);
}
__device__ __forceinline__ f32x4 mfma_bf16(short8_t a, short8_t b, f32x4 c) {
  return __builtin_amdgcn_mfma_f32_16x16x32_bf16(
      __builtin_bit_cast(bf16x8, a), __builtin_bit_cast(bf16x8, b), c, 0, 0, 0);
}
__device__ __forceinline__ float fast_tanh(float x) {
  x = fminf(fmaxf(x, -15.f), 15.f);
  float e = __expf(2.f * x);
  return (e - 1.f) * __builtin_amdgcn_rcpf(e + 1.f);
}

template<int T>
__device__ __forceinline__ void topk_insert(float (&v)[T], int (&ix)[T], float val, int idx) {
  if (val <= v[T-1]) return;
  v[T-1] = val; ix[T-1] = idx;
  #pragma unroll
  for (int j = T-1; j > 0; --j) {
    bool sw = v[j] > v[j-1];
    float tv = sw ? v[j] : v[j-1];  float uv = sw ? v[j-1] : v[j];
    int   ti = sw ? ix[j] : ix[j-1]; int  ui = sw ? ix[j-1] : ix[j];
    v[j-1] = tv; v[j] = uv; ix[j-1] = ti; ix[j] = ui;
  }
}

// ---------------- K0: q = relu(query_feat); qn; q -> bf16 fragment layout ----------------
__global__ __launch_bounds__(256) void k0_prep(const float* __restrict__ qfeat,
                                               float* __restrict__ qr,
                                               unsigned short* __restrict__ qf,
                                               float* __restrict__ qn) {
  int b = blockIdx.x, t = threadIdx.x;
  float s = 0.f;
  #pragma unroll
  for (int p = 0; p < 2; ++p) {
    int k = t + p*256;
    float v = qfeat[b*DD + k];
    v = v > 0.f ? v : 0.f;
    qr[b*DD + k] = v;
    qf[(((b>>4)*64 + (k>>3))*16 + (b&15))*8 + (k&7)] = f2bf(v);
    s += v*v;
  }
  __shared__ float red[4];
  #pragma unroll
  for (int st = 1; st < 64; st <<= 1) s += __shfl_xor(s, st, 64);
  if ((t & 63) == 0) red[t>>6] = s;
  __syncthreads();
  if (t == 0) qn[b] = sqrtf(red[0]+red[1]+red[2]+red[3]);
}

// ---------------- K0b: [512,256] fp32 matrix -> bf16 B-fragment layout ----------------
__global__ __launch_bounds__(256) void k0b_frag(const float* __restrict__ W,
                                                unsigned short* __restrict__ wf) {
  int i = blockIdx.x*256 + threadIdx.x;   // i = d*256 + a, 131072 total
  int d = i >> 8, a = i & 255;
  wf[(((a>>4)*64 + (d>>3))*16 + (a&15))*8 + (d&7)] = f2bf(W[i]);
}

// ---------------- K_qq: qq = relu(q) @ Wq + bq + bm  (256x256, K=512 MFMA) ----------------
__global__ __launch_bounds__(256) void k_qq(const float* __restrict__ Wq,
                                            const unsigned short* __restrict__ qf,
                                            const float* __restrict__ bq,
                                            const float* __restrict__ bm,
                                            float* __restrict__ qq) {
  __shared__ unsigned short wb[64*16*8];   // 16 KB
  int bn = blockIdx.x, t = threadIdx.x;
  int w = t >> 6, l = t & 63, g = l >> 4, c = l & 15;
  #pragma unroll
  for (int i = 0; i < 32; ++i) {
    int d = i*16 + (t>>4); int a = t & 15;
    wb[((d>>3)*16 + a)*8 + (d&7)] = f2bf(Wq[d*AD + bn*16 + a]);
  }
  __syncthreads();
  const short8_t* qf8 = (const short8_t*)qf;
  const short8_t* wb8 = (const short8_t*)wb;
  f32x4 acc[4];
  #pragma unroll
  for (int m = 0; m < 4; ++m) acc[m] = (f32x4){0.f,0.f,0.f,0.f};
  for (int kt = 0; kt < 16; ++kt) {
    short8_t bfr = wb8[(kt*4 + g)*16 + c];
    #pragma unroll
    for (int m = 0; m < 4; ++m) {
      short8_t afr = qf8[((w*4 + m)*64 + kt*4 + g)*16 + c];
      acc[m] = mfma_bf16(afr, bfr, acc[m]);
    }
  }
  int col = bn*16 + c;
  float bias = bq[col] + bm[col];
  #pragma unroll
  for (int m = 0; m < 4; ++m)
    #pragma unroll
    for (int r = 0; r < 4; ++r)
      qq[(w*64 + m*16 + g*4 + r)*AD + col] = acc[m][r] + bias;
}

// ---------------- K1: coarse bf16 GEMM (keys=A, queries=B) + in-register per-lane top-3 ----------------
__global__ __launch_bounds__(256) void k1_sim(const float* __restrict__ keys,
                                              const unsigned short* __restrict__ qf,
                                              unsigned int* __restrict__ cand) {
  __shared__ unsigned short bt[64*72];   // key tile bf16
  __shared__ float kpart[64*16];
  __shared__ float invkn[64];

  int b = blockIdx.x, t = threadIdx.x;
  int kb0 = b*KB;
  int w = t >> 6, l = t & 63, g = l >> 4, c = l & 15;

  f32x4 acc[4][4];   // [key-tile m][query-tile n]
  #pragma unroll
  for (int m = 0; m < 4; ++m)
    #pragma unroll
    for (int n = 0; n < 4; ++n) acc[m][n] = (f32x4){0.f,0.f,0.f,0.f};
  float ksq[4] = {0.f,0.f,0.f,0.f};

  const short8_t* qf8 = (const short8_t*)qf;

  for (int st8 = 0; st8 < 8; ++st8) {
    __syncthreads();
    #pragma unroll
    for (int i = 0; i < 4; ++i) {
      int f = t + i*256;
      int r = f >> 4, c4 = f & 15;
      int key = kb0 + r;
      float4 v = make_float4(0.f,0.f,0.f,0.f);
      if (key < NKEY) v = *(const float4*)(keys + (size_t)key*DD + st8*64 + c4*4);
      ksq[i] += v.x*v.x + v.y*v.y + v.z*v.z + v.w*v.w;
      ushort4 h; h.x = f2bf_n(v.x); h.y = f2bf_n(v.y); h.z = f2bf_n(v.z); h.w = f2bf_n(v.w);
      *(ushort4*)&bt[r*72 + c4*4] = h;
    }
    __syncthreads();
    #pragma unroll
    for (int ks = 0; ks < 2; ++ks) {
      short8_t af[4], bf[4];
      int kt = st8*8 + ks*4 + g;
      #pragma unroll
      for (int m = 0; m < 4; ++m) af[m] = *(const short8_t*)&bt[(m*16 + c)*72 + ks*32 + g*8];
      #pragma unroll
      for (int n = 0; n < 4; ++n) bf[n] = qf8[((w*4 + n)*64 + kt)*16 + c];
      #pragma unroll
      for (int m = 0; m < 4; ++m)
        #pragma unroll
        for (int n = 0; n < 4; ++n) acc[m][n] = mfma_bf16(af[m], bf[n], acc[m][n]);
    }
  }

  // key inverse norms
  #pragma unroll
  for (int i = 0; i < 4; ++i) kpart[((t>>4) + 16*i)*16 + (t&15)] = ksq[i];
  __syncthreads();
  if (t < 64) {
    float s2 = 0.f;
    #pragma unroll
    for (int i = 0; i < 16; ++i) s2 += kpart[t*16 + i];
    invkn[t] = s2 > 0.f ? rsqrtf(s2) : 0.f;
  }
  __syncthreads();

  float ikv[16];
  #pragma unroll
  for (int m = 0; m < 4; ++m)
    #pragma unroll
    for (int r = 0; r < 4; ++r) ikv[m*4 + r] = invkn[m*16 + g*4 + r];

  // per-lane branchless top-3 of the lane's 16 keys, per query column
  #pragma unroll
  for (int n = 0; n < 4; ++n) {
    float v1 = -3.0e38f, v2 = -3.0e38f, v3 = -3.0e38f;
    int   i1 = 0, i2 = 0, i3 = 0;
    #pragma unroll
    for (int m = 0; m < 4; ++m)
      #pragma unroll
      for (int r = 0; r < 4; ++r) {
        int lid = m*16 + g*4 + r;
        bool valid = (kb0 + lid) < NKEY;
        float v = valid ? acc[m][n][r] * ikv[m*4 + r] : -3.0e38f;
        bool gt1 = v > v1, gt2 = v > v2, gt3 = v > v3;
        v3 = gt2 ? v2 : (gt3 ? v : v3);  i3 = gt2 ? i2 : (gt3 ? lid : i3);
        v2 = gt1 ? v1 : (gt2 ? v : v2);  i2 = gt1 ? i1 : (gt2 ? lid : i2);
        v1 = gt1 ? v  : v1;              i1 = gt1 ? lid : i1;
      }
    int q = w*64 + n*16 + c;
    unsigned int base = ((unsigned int)q*NB + (unsigned int)b)*12u + (unsigned int)g*3u;
    cand[base + 0] = ((unsigned int)__half_as_ushort(__float2half(v1)) << 16) | (unsigned int)i1;
    cand[base + 1] = ((unsigned int)__half_as_ushort(__float2half(v2)) << 16) | (unsigned int)i2;
    cand[base + 2] = ((unsigned int)__half_as_ushort(__float2half(v3)) << 16) | (unsigned int)i3;
  }
}

// ---------------- K2a: high-occupancy candidate reduce (8 blocks/query, per-wave top-12) ----------------
__global__ __launch_bounds__(256) void k2a_reduce(const unsigned int* __restrict__ cand,
                                                  int* __restrict__ wtop) {
  int bid = blockIdx.x;
  int q = bid >> 3, p = bid & 7;
  int t = threadIdx.x, w = t >> 6, l = t & 63;
  const unsigned int* cq = cand + (size_t)q * CPQ;

  const int PER_PART = (CPQ + NPART - 1) / NPART;   // 2345
  const int PER_WAVE = (PER_PART + 3) / 4;          // 587
  int pbase = p * PER_PART;
  int start = pbase + w * PER_WAVE;
  int end   = pbase + PER_PART;
  if (start + PER_WAVE < end) end = start + PER_WAVE;
  if (end > CPQ) end = CPQ;

  float v[TLA]; int ix[TLA];
  #pragma unroll
  for (int j = 0; j < TLA; ++j) { v[j] = -INFINITY; ix[j] = -1; }
  for (int i = start + l; i < end; i += 64) {
    unsigned int pk = cq[i];
    float val = __half2float(__ushort_as_half((unsigned short)(pk >> 16)));
    int bb = i / 12;                       // compiler magic-mul
    int idx = (bb << 6) | (int)(pk & 63u);
    topk_insert<TLA>(v, ix, val, idx);
  }

  // wave merge: exact wave top-WTOP (heads of sorted per-lane lists)
  int obase = (q * NPART + p) * 4 * WTOP + w * WTOP;
  for (int it = 0; it < WTOP; ++it) {
    float bv = v[0]; int bx = ix[0]; int bl = l;
    #pragma unroll
    for (int sft = 1; sft < 64; sft <<= 1) {
      float ov = __shfl_xor(bv, sft, 64);
      int  oxx = __shfl_xor(bx, sft, 64);
      int  ol  = __shfl_xor(bl, sft, 64);
      bool take = (ov > bv) || (ov == bv && ol < bl);
      if (take) { bv = ov; bx = oxx; bl = ol; }
    }
    if (l == 0) wtop[obase + it] = bx;
    if (l == bl) {
      #pragma unroll
      for (int j = 0; j < TLA-1; ++j) { v[j] = v[j+1]; ix[j] = ix[j+1]; }
      v[TLA-1] = -INFINITY; ix[TLA-1] = -1;
    }
  }
}

// ---------------- K2b: exact fp32 rescore of 384 + final top-32 ----------------
__global__ __launch_bounds__(256) void k2b_rescore(const int* __restrict__ wtop,
                                                   const float* __restrict__ qr,
                                                   const float* __restrict__ qn,
                                                   const float* __restrict__ keys,
                                                   int* __restrict__ fidx) {
  int q = blockIdx.x, t = threadIdx.x, w = t >> 6, l = t & 63;
  __shared__ float simx[NC2];
  __shared__ int   sidx[NC2];

  // each lane holds its 8-float slice of the query row
  const float4* q4 = (const float4*)(qr + (size_t)q*DD + l*8);
  float4 qa0 = q4[0], qa1 = q4[1];
  float qnv = qn[q];

  for (int i = 0; i < NC2/4; ++i) {       // 96 candidates per wave
    int ci = i*4 + w;
    int idx = wtop[q*NC2 + ci];
    bool bad = (idx < 0) || (idx >= NKEY);
    int cidx = bad ? 0 : idx;
    const float4* kr = (const float4*)(keys + (size_t)cidx*DD + l*8);
    float4 k0 = kr[0], k1 = kr[1];
    float dot = qa0.x*k0.x + qa0.y*k0.y + qa0.z*k0.z + qa0.w*k0.w
              + qa1.x*k1.x + qa1.y*k1.y + qa1.z*k1.z + qa1.w*k1.w;
    float ks  = k0.x*k0.x + k0.y*k0.y + k0.z*k0.z + k0.w*k0.w
              + k1.x*k1.x + k1.y*k1.y + k1.z*k1.z + k1.w*k1.w;
    #pragma unroll
    for (int sft = 1; sft < 64; sft <<= 1) {
      dot += __shfl_xor(dot, sft, 64);
      ks  += __shfl_xor(ks,  sft, 64);
    }
    if (l == 0) {
      float den = fmaxf(qnv * sqrtf(ks), 1e-8f);
      simx[ci] = bad ? -1e30f : dot/den;
      sidx[ci] = cidx;
    }
  }
  __syncthreads();

  // wave 0: exact top-32 of 384, tie-break value desc then index asc (lax.top_k)
  if (w == 0) {
    float a[6]; int id[6];
    #pragma unroll
    for (int j = 0; j < 6; ++j) { a[j] = simx[j*64 + l]; id[j] = sidx[j*64 + l]; }
    for (int it = 0; it < KSEL; ++it) {
      float bv = a[0]; int bx = id[0]; int bslot = 0;
      #pragma unroll
      for (int j = 1; j < 6; ++j) {
        bool take = (a[j] > bv) || (a[j] == bv && id[j] < bx);
        bv = take ? a[j] : bv; bx = take ? id[j] : bx; bslot = take ? j : bslot;
      }
      int bl = l;
      #pragma unroll
      for (int sft = 1; sft < 64; sft <<= 1) {
        float ov = __shfl_xor(bv, sft, 64);
        int  oxx = __shfl_xor(bx, sft, 64);
        int  ol  = __shfl_xor(bl, sft, 64);
        bool take = (ov > bv) || (ov == bv && oxx < bx);
        if (take) { bv = ov; bx = oxx; bl = ol; }
      }
      if (l == 0) fidx[q*KSEL + it] = bx;
      if (l == bl) {
        #pragma unroll
        for (int j = 0; j < 6; ++j) if (j == bslot) a[j] = -INFINITY;
      }
    }
  }
}

// ---------------- K3a: gather knn, MFMA knn@Wm, tanh/score/softmax, attended -> attf ----------------
__global__ __launch_bounds__(256) void k3_attn(const float* __restrict__ keys,
                                               const float* __restrict__ qq,
                                               const unsigned short* __restrict__ wmf,
                                               const int* __restrict__ fidx,
                                               const float* __restrict__ Ws,
                                               const float* __restrict__ bsc,
                                               unsigned short* __restrict__ attf) {
  int q = blockIdx.x, t = threadIdx.x, w = t >> 6, l = t & 63, g = l >> 4, c = l & 15;
  __shared__ float qqb[256];
  __shared__ float wsl[256];
  __shared__ unsigned short knnb[32*520];
  __shared__ float spart[4][32];
  __shared__ float wexp[32];
  __shared__ int fl[32];

  if (t < 32) fl[t] = fidx[q*KSEL + t];
  qqb[t] = qq[q*AD + t];
  wsl[t] = Ws[t];
  __syncthreads();

  for (int r = 0; r < 32; ++r) {
    int row = fl[r];
    #pragma unroll
    for (int p = 0; p < 2; ++p) {
      int d = t + p*256;
      knnb[r*520 + d] = f2bf(keys[(size_t)row*DD + d]);
    }
  }
  __syncthreads();

  f32x4 acc[2][4];
  #pragma unroll
  for (int m = 0; m < 2; ++m)
    #pragma unroll
    for (int n = 0; n < 4; ++n) acc[m][n] = (f32x4){0.f,0.f,0.f,0.f};
  const short8_t* wmf8 = (const short8_t*)wmf;
  for (int ks = 0; ks < 16; ++ks) {
    short8_t af[2], bf[4];
    #pragma unroll
    for (int m = 0; m < 2; ++m) af[m] = *(const short8_t*)&knnb[(m*16 + c)*520 + ks*32 + g*8];
    #pragma unroll
    for (int n = 0; n < 4; ++n) bf[n] = wmf8[((w*4 + n)*64 + ks*4 + g)*16 + c];
    #pragma unroll
    for (int m = 0; m < 2; ++m)
      #pragma unroll
      for (int n = 0; n < 4; ++n) acc[m][n] = mfma_bf16(af[m], bf[n], acc[m][n]);
  }

  float p[8] = {0.f,0.f,0.f,0.f,0.f,0.f,0.f,0.f};
  #pragma unroll
  for (int n = 0; n < 4; ++n) {
    int a = w*64 + n*16 + c;
    float qv = qqb[a], wv = wsl[a];
    #pragma unroll
    for (int m = 0; m < 2; ++m)
      #pragma unroll
      for (int r = 0; r < 4; ++r)
        p[m*4 + r] += fast_tanh(acc[m][n][r] + qv) * wv;
  }
  #pragma unroll
  for (int sft = 1; sft < 16; sft <<= 1)
    #pragma unroll
    for (int i = 0; i < 8; ++i) p[i] += __shfl_xor(p[i], sft, 64);
  if (c == 0) {
    #pragma unroll
    for (int m = 0; m < 2; ++m)
      #pragma unroll
      for (int r = 0; r < 4; ++r) spart[w][m*16 + g*4 + r] = p[m*4 + r];
  }
  __syncthreads();

  if (t < 32) {
    float s = spart[0][t] + spart[1][t] + spart[2][t] + spart[3][t] + bsc[0];
    float mx = s;
    #pragma unroll
    for (int sft = 1; sft < 32; sft <<= 1) mx = fmaxf(mx, __shfl_xor(mx, sft, 64));
    float e = __expf(s - mx);
    float su = e;
    #pragma unroll
    for (int sft = 1; sft < 32; sft <<= 1) su += __shfl_xor(su, sft, 64);
    wexp[t] = e / su;
  }
  __syncthreads();

  #pragma unroll
  for (int pth = 0; pth < 2; ++pth) {
    int d = t + pth*256;
    float s = 0.f;
    #pragma unroll
    for (int k = 0; k < 32; ++k) s += wexp[k] * bf2f(knnb[k*520 + d]);
    attf[(((q>>4)*64 + (d>>3))*16 + (q&15))*8 + (d&7)] = f2bf(s);
  }
}

// ---------------- K3b: out = [q, attended] @ Wc + bc  (256x100, K=1024 MFMA) ----------------
__global__ __launch_bounds__(256) void k3b_cls(const float* __restrict__ Wc,
                                               const unsigned short* __restrict__ qf,
                                               const unsigned short* __restrict__ attf,
                                               const float* __restrict__ bc,
                                               float* __restrict__ out) {
  __shared__ unsigned short wb[128*16*8];   // 32 KB
  int bn = blockIdx.x, t = threadIdx.x;
  int w = t >> 6, l = t & 63, g = l >> 4, c = l & 15;
  #pragma unroll
  for (int i = 0; i < 64; ++i) {
    int d = i*16 + (t>>4); int a = t & 15;
    int col = bn*16 + a;
    float vv = (col < CD) ? Wc[d*CD + col] : 0.f;
    wb[((d>>3)*16 + a)*8 + (d&7)] = f2bf(vv);
  }
  __syncthreads();
  const short8_t* qf8 = (const short8_t*)qf;
  const short8_t* af8 = (const short8_t*)attf;
  const short8_t* wb8 = (const short8_t*)wb;
  f32x4 acc[4];
  #pragma unroll
  for (int m = 0; m < 4; ++m) acc[m] = (f32x4){0.f,0.f,0.f,0.f};
  for (int kt = 0; kt < 32; ++kt) {
    short8_t bfr = wb8[(kt*4 + g)*16 + c];
    const short8_t* asrc = (kt < 16) ? qf8 : af8;
    int kbase = (kt < 16) ? (kt*4 + g) : ((kt-16)*4 + g);
    #pragma unroll
    for (int m = 0; m < 4; ++m) {
      short8_t afr = asrc[((w*4 + m)*64 + kbase)*16 + c];
      acc[m] = mfma_bf16(afr, bfr, acc[m]);
    }
  }
  int col = bn*16 + c;
  if (col < CD) {
    float bias = bc[col];
    #pragma unroll
    for (int m = 0; m < 4; ++m)
      #pragma unroll
      for (int r = 0; r < 4; ++r)
        out[(w*64 + m*16 + g*4 + r)*CD + col] = acc[m][r] + bias;
  }
}

// ---------------- launch ----------------
extern "C" void kernel_launch(void* const* d_in, const int* in_sizes, int n_in,
                              void* d_out, int out_size, void* d_ws, size_t ws_size,
                              hipStream_t stream) {
  const float* qfeat = (const float*)d_in[0];
  const float* keys  = (const float*)d_in[1];
  const float* Wq    = (const float*)d_in[2];
  const float* bq    = (const float*)d_in[3];
  const float* Wm    = (const float*)d_in[4];
  const float* bm    = (const float*)d_in[5];
  const float* Ws    = (const float*)d_in[6];
  const float* bsc   = (const float*)d_in[7];
  const float* Wc    = (const float*)d_in[8];
  const float* bc    = (const float*)d_in[9];
  float* out = (float*)d_out;

  char* ws = (char*)d_ws;
  unsigned short* qf   = (unsigned short*)(ws + 0);          // 262144 B
  float*          qr   = (float*)(ws + 262144);              // 524288 B
  float*          qn   = (float*)(ws + 786432);              // 1024 B
  unsigned short* wmf  = (unsigned short*)(ws + 787456);     // 262144 B
  float*          qq   = (float*)(ws + 1049600);             // 262144 B
  unsigned short* attf = (unsigned short*)(ws + 1311744);    // 262144 B
  int*            fidx = (int*)(ws + 1573888);               // 32768 B
  int*            wtop = (int*)(ws + 1606656);               // 393216 B
  unsigned int*   cand = (unsigned int*)(ws + 1999872);      // 19203072 B

  k0_prep   <<<BQ,       256, 0, stream>>>(qfeat, qr, qf, qn);
  k0b_frag  <<<512,      256, 0, stream>>>(Wm, wmf);
  k_qq      <<<16,       256, 0, stream>>>(Wq, qf, bq, bm, qq);
  k1_sim    <<<NB,       256, 0, stream>>>(keys, qf, cand);
  k2a_reduce<<<BQ*NPART, 256, 0, stream>>>(cand, wtop);
  k2b_rescore<<<BQ,      256, 0, stream>>>(wtop, qr, qn, keys, fidx);
  k3_attn   <<<BQ,       256, 0, stream>>>(keys, qq, wmf, fidx, Ws, bsc, attf);
  k3b_cls   <<<7,        256, 0, stream>>>(Wc, qf, attf, bc, out);
}